// Round 22
// baseline (290.786 us; speedup 1.0000x reference)
//
#include <hip/hip_runtime.h>

// Problem constants (N=8192 rows, D=256 features)
#define NN 8192
#define DD 256
#define ND_ (NN * DD)

#define NEG_SLOPE 0.1f

typedef _Float16 half8 __attribute__((ext_vector_type(8)));
typedef _Float16 half4 __attribute__((ext_vector_type(4)));
typedef float f32x4 __attribute__((ext_vector_type(4)));
typedef float f32x16 __attribute__((ext_vector_type(16)));

// async global->LDS, 16B per lane; lds dst = wave-uniform base + lane*16,
// global src = PER-LANE address (must include lane offset!)
__device__ __forceinline__ void ld_g2l16(const void* g, void* l) {
    __builtin_amdgcn_global_load_lds(
        (const __attribute__((address_space(1))) void*)g,
        (__attribute__((address_space(3))) void*)l, 16, 0, 0);
}

__device__ __forceinline__ unsigned pkhalf2(_Float16 a, _Float16 b) {
    unsigned short ua = __builtin_bit_cast(unsigned short, a);
    unsigned short ub = __builtin_bit_cast(unsigned short, b);
    return (unsigned)ua | ((unsigned)ub << 16);
}

// ---------------------------------------------------------------------------
// prep_split: f16 (hi-only) u = h+d, v = h-d in the SWIZZLED k-block layout
// agg consumes via linear global_load_lds:
//   element (c, k):  kb = k>>5, gd = (k>>3)&3, slot = gd ^ ((c>>1)&3)
//   offset = kb*8192 + c*32 + slot*8 + (k&7)      (f16 units)
// Grid 128 node-tiles x 4 feature-tiles = 512 blocks, 256 threads.
// ---------------------------------------------------------------------------
__global__ __launch_bounds__(256, 4)
void prep_split_kernel(const float* __restrict__ h, const float* __restrict__ d,
                       _Float16* __restrict__ uS_hi, _Float16* __restrict__ vS_hi) {
    __shared__ float s_h[64 * 68];
    __shared__ float s_d[64 * 68];
    const int b  = blockIdx.x;
    const int kt = b >> 2;          // node-tile 0..127 (64 nodes)
    const int ct = b & 3;           // feature-tile 0..3 (64 features)
    const int k0 = kt * 64;
    const int c0 = ct * 64;
    const int t  = threadIdx.x;

#pragma unroll
    for (int e = 0; e < 4; ++e) {
        int idx = e * 256 + t;
        int r   = idx >> 4;                  // node 0..63
        int c4  = (idx & 15) << 2;           // feature 0..60
        float4 hv = *(const float4*)&h[(size_t)(k0 + r) * DD + c0 + c4];
        float4 dv = *(const float4*)&d[(size_t)(k0 + r) * DD + c0 + c4];
        *(float4*)&s_h[r * 68 + c4] = hv;
        *(float4*)&s_d[r * 68 + c4] = dv;
    }
    __syncthreads();

#pragma unroll
    for (int e = 0; e < 2; ++e) {
        int idx = e * 256 + t;
        int c   = idx >> 3;                  // feature-in-tile 0..63
        int seg = idx & 7;                   // node chunk of 8 (k' = seg*8)
        half8 uh, vh;
#pragma unroll
        for (int m = 0; m < 8; ++m) {
            float hh = s_h[(seg * 8 + m) * 68 + c];
            float dd = s_d[(seg * 8 + m) * 68 + c];
            uh[m] = (_Float16)(hh + dd);
            vh[m] = (_Float16)(hh - dd);
        }
        int    cg   = c0 + c;
        int    kb   = kt * 2 + (seg >> 2);
        int    slot = (seg & 3) ^ ((cg >> 1) & 3);
        size_t go   = (size_t)kb * 8192 + (size_t)cg * 32 + slot * 8;
        *(half8*)&uS_hi[go] = uh;
        *(half8*)&vS_hi[go] = vh;
    }
}

// ---------------------------------------------------------------------------
// agg_mfma: f16x1 MFMA (32x32x16) split-K(2) partials:
//   P = (A + A^T) @ u      Q = (A^T - A) @ v       (hi terms only)
// stored f16 in Pbuf/Qbuf [2 halves][NN][DD].
//
// LDS-TRAFFIC-OPTIMIZED: 256-thr blocks (4 waves: w0/w1 P, w2/w3 Q), each
// wave owns a 64x64 band -> 8 MFMA per 8 ds_read_b128 (1.0 reads/MFMA vs
// 1.5 at 64x32). SD+B double-buffered, one raw barrier/iter (R18 protocol):
//   build S/D(it) from CUR [alpha 2 iters old -> auto-wait free]
//   ds_write -> SD[p]
//   vmcnt(12) [queue = gl(it)^4 + alpha(it+1)^12 -> retires own gl_lds(it)]
//   lgkmcnt(0) ; s_barrier [publishes SD[p] + B[p]]
//   gl_lds B(it+1)->B[1-p] ; LOAD_ALPHA(CUR, it+2)
//   8 MFMA on SD[p], B[p]
// LDS 52KB -> __launch_bounds__(256,3): 3 blocks/CU (156KB LDS).
// Block 64r x 128c, BK=32, 128 iters. Grid: 512 = 128 rb x 2 cb x 2 kh.
// ---------------------------------------------------------------------------
__global__ __launch_bounds__(256, 3)
void agg_mfma_kernel(const float* __restrict__ alpha,
                     const _Float16* __restrict__ uS_hi, const _Float16* __restrict__ vS_hi,
                     _Float16* __restrict__ Pbuf,   // [2][NN][DD]
                     _Float16* __restrict__ Qbuf) { // [2][NN][DD]
    // LDS carve (bytes):
    //  SD[2]: {sS [64r][40kp], sD [64r][40kp]} f16    2*10240 = 20480
    //  B [2]: {Bu [128c][32k], Bv [128c][32k]} f16    2*16384 = 32768 -> 53248
    __shared__ __align__(16) unsigned char smem[53248];

    const int raw  = blockIdx.x;
    const int kh   = raw & 1;
    const int cb   = (raw >> 3) & 1;
    const int rb   = ((raw >> 1) & 3) | ((raw >> 4) << 2);
    const int I0   = rb * 64;
    const int C0   = cb * 128;
    const int t    = threadIdx.x;
    const int w    = t >> 6;               // 0..3
    const int lane = t & 63;

    const bool isP = (w < 2);
    const int  cw  = w & 1;                // 64-col band within the 128

    f32x16 acc00, acc01, acc10, acc11;     // [row-frag][col-frag]
#pragma unroll
    for (int r = 0; r < 16; ++r) {
        acc00[r] = 0.f; acc01[r] = 0.f; acc10[r] = 0.f; acc11[r] = 0.f;
    }

    // build / mfma index precompute (256 thr = 16 rbase x 16 kp)
    const int rbase = t & 15;
    const int kp    = (t >> 4) & 15;       // k-pair: k = 2kp, 2kp+1
    const int row0  = rbase;
    const int row1  = rbase + 16;
    const int row2  = rbase + 32;
    const int row3  = rbase + 48;
    const int lrow  = lane & 31;
    const int lk    = (lane >> 5) << 3;    // 0 or 8
    const int kbase = kh * (NN / 2);

    // ---- alpha set: 12 loads (8 col scalars + 4 row float2) = 16 VGPRs ----
#define LOAD_ALPHA(S, IT)                                                        \
    {                                                                            \
        const int kk0 = kbase + (IT) * 32 + 2 * kp;                              \
        size_t z0 = (size_t)kk0 * NN + I0;                                       \
        S##c00 = alpha[z0 + row0];      S##c10 = alpha[z0 + NN + row0];          \
        S##c01 = alpha[z0 + row1];      S##c11 = alpha[z0 + NN + row1];          \
        S##c02 = alpha[z0 + row2];      S##c12 = alpha[z0 + NN + row2];          \
        S##c03 = alpha[z0 + row3];      S##c13 = alpha[z0 + NN + row3];          \
        S##r0 = *(const float2*)&alpha[(size_t)(I0 + row0) * NN + kk0];          \
        S##r1 = *(const float2*)&alpha[(size_t)(I0 + row1) * NN + kk0];          \
        S##r2 = *(const float2*)&alpha[(size_t)(I0 + row2) * NN + kk0];          \
        S##r3 = *(const float2*)&alpha[(size_t)(I0 + row3) * NN + kk0];          \
    }

    // One iteration at parity P consuming alpha set CUR (R18 protocol).
#define ITER(CUR, P, IT)                                                         \
    {                                                                            \
        /* build S/D f16 pairs (CUR ~2 iters old -> auto-wait free) */           \
        unsigned s0 = pkhalf2((_Float16)(CUR##c00 + CUR##r0.x), (_Float16)(CUR##c10 + CUR##r0.y)); \
        unsigned d0 = pkhalf2((_Float16)(CUR##c00 - CUR##r0.x), (_Float16)(CUR##c10 - CUR##r0.y)); \
        unsigned s1 = pkhalf2((_Float16)(CUR##c01 + CUR##r1.x), (_Float16)(CUR##c11 + CUR##r1.y)); \
        unsigned d1 = pkhalf2((_Float16)(CUR##c01 - CUR##r1.x), (_Float16)(CUR##c11 - CUR##r1.y)); \
        unsigned s2 = pkhalf2((_Float16)(CUR##c02 + CUR##r2.x), (_Float16)(CUR##c12 + CUR##r2.y)); \
        unsigned d2 = pkhalf2((_Float16)(CUR##c02 - CUR##r2.x), (_Float16)(CUR##c12 - CUR##r2.y)); \
        unsigned s3 = pkhalf2((_Float16)(CUR##c03 + CUR##r3.x), (_Float16)(CUR##c13 + CUR##r3.y)); \
        unsigned d3 = pkhalf2((_Float16)(CUR##c03 - CUR##r3.x), (_Float16)(CUR##c13 - CUR##r3.y)); \
        /* ds_write S/D -> SD[P] (pitch 40 f16 = 20 u32/row) */                  \
        {                                                                        \
            unsigned* wS = (unsigned*)(smem + (P) * 10240);                      \
            unsigned* wD = (unsigned*)(smem + (P) * 10240 + 5120);               \
            wS[row0 * 20 + kp] = s0;  wD[row0 * 20 + kp] = d0;                   \
            wS[row1 * 20 + kp] = s1;  wD[row1 * 20 + kp] = d1;                   \
            wS[row2 * 20 + kp] = s2;  wD[row2 * 20 + kp] = d2;                   \
            wS[row3 * 20 + kp] = s3;  wD[row3 * 20 + kp] = d3;                   \
        }                                                                        \
        /* retire own gl_lds(IT) [queue: gl(IT)^4 + alpha(IT+1)^12]; flush */    \
        asm volatile("s_waitcnt vmcnt(12)" ::: "memory");                        \
        asm volatile("s_waitcnt lgkmcnt(0)" ::: "memory");                       \
        __builtin_amdgcn_s_barrier();                                            \
        __builtin_amdgcn_sched_barrier(0);                                       \
        /* gl_lds B(IT+1) -> B[1-P] (post-barrier: MFMA(IT-1) readers done) */   \
        {                                                                        \
            size_t gb = (size_t)(kh * 128 + (((IT) + 1) & 127)) * 8192 +         \
                        cb * 4096 + (size_t)(w * 1024 + lane * 8);               \
            unsigned char* bN = smem + 20480 + (1 - (P)) * 16384;                \
            ld_g2l16(uS_hi + gb,       bN + w * 2048);                           \
            ld_g2l16(uS_hi + gb + 512, bN + w * 2048 + 1024);                    \
            ld_g2l16(vS_hi + gb,       bN + 8192 + w * 2048);                    \
            ld_g2l16(vS_hi + gb + 512, bN + 8192 + w * 2048 + 1024);             \
        }                                                                        \
        __builtin_amdgcn_sched_barrier(0);  /* pin: gl_lds BEFORE alpha */       \
        /* prefetch alpha(IT+2) back into CUR (values consumed above) */         \
        LOAD_ALPHA(CUR, (((IT) + 2) & 127))                                      \
        __builtin_amdgcn_sched_barrier(0);                                       \
        /* 8 MFMA (32x32x16), f16x1 on SD[P], B[P]; 64x64 wave band */           \
        {                                                                        \
            const unsigned char* sd = smem + (P) * 10240;                        \
            const _Float16* aSD = (const _Float16*)(sd + (isP ? 0 : 5120));      \
            const unsigned char* bb = smem + 20480 + (P) * 16384;                \
            const _Float16* bB  = (const _Float16*)(bb + (isP ? 0 : 8192));      \
            __builtin_amdgcn_s_setprio(1);                                       \
            _Pragma("unroll")                                                    \
            for (int s = 0; s < 2; ++s) {                                        \
                half8 aH0 = *(const half8*)&aSD[(lrow) * 40 + s * 16 + lk];      \
                half8 aH1 = *(const half8*)&aSD[(32 + lrow) * 40 + s * 16 + lk]; \
                int gd = s * 2 + (lane >> 5);                                    \
                int c0l = cw * 64 + lrow;                                        \
                int sl0 = gd ^ ((c0l >> 1) & 3);                                 \
                half8 bH0 = *(const half8*)&bB[c0l * 32 + sl0 * 8];              \
                int c1l = cw * 64 + 32 + lrow;                                   \
                int sl1 = gd ^ ((c1l >> 1) & 3);                                 \
                half8 bH1 = *(const half8*)&bB[c1l * 32 + sl1 * 8];              \
                acc00 = __builtin_amdgcn_mfma_f32_32x32x16_f16(aH0, bH0, acc00, 0, 0, 0); \
                acc10 = __builtin_amdgcn_mfma_f32_32x32x16_f16(aH1, bH0, acc10, 0, 0, 0); \
                acc01 = __builtin_amdgcn_mfma_f32_32x32x16_f16(aH0, bH1, acc01, 0, 0, 0); \
                acc11 = __builtin_amdgcn_mfma_f32_32x32x16_f16(aH1, bH1, acc11, 0, 0, 0); \
            }                                                                    \
            __builtin_amdgcn_s_setprio(0);                                       \
        }                                                                        \
    }

    float Ac00, Ac10, Ac01, Ac11, Ac02, Ac12, Ac03, Ac13;
    float2 Ar0, Ar1, Ar2, Ar3;
    float Bc00, Bc10, Bc01, Bc11, Bc02, Bc12, Bc03, Bc13;
    float2 Br0, Br1, Br2, Br3;

    // ---- prologue: gl_lds B(0)->slot0 FIRST (oldest), then alpha(0),(1) ----
    {
        size_t gb = (size_t)(kh * 128) * 8192 + cb * 4096 +
                    (size_t)(w * 1024 + lane * 8);
        unsigned char* bN = smem + 20480;
        ld_g2l16(uS_hi + gb,       bN + w * 2048);
        ld_g2l16(uS_hi + gb + 512, bN + w * 2048 + 1024);
        ld_g2l16(vS_hi + gb,       bN + 8192 + w * 2048);
        ld_g2l16(vS_hi + gb + 512, bN + 8192 + w * 2048 + 1024);
    }
    LOAD_ALPHA(A, 0)
    LOAD_ALPHA(B, 1)

    for (int it2 = 0; it2 < 64; ++it2) {
        ITER(A, 0, (it2 * 2))
        ITER(B, 1, (it2 * 2 + 1))
    }
#undef ITER
#undef LOAD_ALPHA

    // ---- epilogue: write f16 partials ----
    // C/D layout (32x32): col = lane&31, row = (reg&3) + 8*(reg>>2) + 4*(lane>>5)
    _Float16* dst = (isP ? Pbuf : Qbuf) + (size_t)kh * ND_;
    const int colw0 = C0 + cw * 64 + (lane & 31);
#pragma unroll
    for (int reg = 0; reg < 16; ++reg) {
        int rr = (reg & 3) + ((reg >> 2) << 3) + ((lane >> 5) << 2);
        dst[(size_t)(I0 + rr) * DD + colw0]           = (_Float16)acc00[reg];
        dst[(size_t)(I0 + 32 + rr) * DD + colw0]      = (_Float16)acc10[reg];
        dst[(size_t)(I0 + rr) * DD + colw0 + 32]      = (_Float16)acc01[reg];
        dst[(size_t)(I0 + 32 + rr) * DD + colw0 + 32] = (_Float16)acc11[reg];
    }
}

// ---------------------------------------------------------------------------
// stageB: combine P/Q partials into agg, then
//   out = leaky_relu( agg @ W1 + Y @ W2 )
// Block tile 64 x 128, 256 threads, 4x8 accum/thread, K=256 in BK=32 chunks.
// Grid 512: sel = b>>8 (0 = head output, 1 = dependent output).
// ---------------------------------------------------------------------------
__global__ __launch_bounds__(256, 4)
void stageB_kernel(const _Float16* __restrict__ Pbuf, const _Float16* __restrict__ Qbuf,
                   const float* __restrict__ head, const float* __restrict__ dep,
                   const float* __restrict__ alpha,
                   const float* __restrict__ Wah, const float* __restrict__ Wad,
                   const float* __restrict__ Wch, const float* __restrict__ Wcd,
                   float* __restrict__ out) {
    __shared__ float smem2[12544];
    __shared__ float s_dg[64];
    float* s_x  = smem2;            // [32][68] transposed X tile
    float* s_y  = smem2 + 2176;     // [32][68]
    float* s_w1 = smem2 + 4352;     // [32][128]
    float* s_w2 = smem2 + 8448;     // [32][128] -> 12544

    int b   = blockIdx.x;
    int sel = b >> 8;
    int rem = b & 255;
    int rb  = rem >> 1;
    int cb  = rem & 1;
    int I0  = rb * 64;
    int C0  = cb * 128;

    const float* Y  = sel ? dep : head;
    const float* W1 = sel ? Wad : Wah;
    const float* W2 = sel ? Wcd : Wch;
    float* dst = out + sel * ND_;

    int t  = threadIdx.x;
    int rg = t & 15, cg = t >> 4;
    int r0 = rg * 4, c0 = cg * 8;

    if (t < 64) s_dg[t] = alpha[(size_t)(I0 + t) * NN + I0 + t];

    float acc[4][8];
#pragma unroll
    for (int i = 0; i < 4; ++i)
#pragma unroll
        for (int j = 0; j < 8; ++j) acc[i][j] = 0.0f;

    for (int it = 0; it < 8; ++it) {
        int k0 = it * 32;
        __syncthreads();
#pragma unroll
        for (int e = 0; e < 2; ++e) {
            int idx = e * 256 + t;
            int r   = idx >> 3;              // 0..63
            int k4  = (idx & 7) << 2;        // 0..28
            size_t go = (size_t)(I0 + r) * DD + k0 + k4;
            half4 p0 = *(const half4*)&Pbuf[go];
            half4 p1 = *(const half4*)&Pbuf[ND_ + go];
            half4 q0 = *(const half4*)&Qbuf[go];
            half4 q1 = *(const half4*)&Qbuf[ND_ + go];
            float4 hv = *(const float4*)&head[go];
            float4 dv = *(const float4*)&dep[go];
            float dgv = s_dg[r];
            float hj[4] = {hv.x, hv.y, hv.z, hv.w};
            float dj[4] = {dv.x, dv.y, dv.z, dv.w};
#pragma unroll
            for (int j = 0; j < 4; ++j) {
                float Pv = (float)p0[j] + (float)p1[j];
                float Qv = (float)q0[j] + (float)q1[j];
                float uu = hj[j] + dj[j];
                float x  = (sel ? 0.5f * (Pv - Qv) : 0.5f * (Pv + Qv)) - dgv * uu;
                s_x[(k4 + j) * 68 + r] = x;
                s_y[(k4 + j) * 68 + r] = sel ? dj[j] : hj[j];
            }
        }
#pragma unroll
        for (int e = 0; e < 4; ++e) {
            int idx = e * 256 + t;
            int kkk = idx >> 5;
            int c4  = (idx & 31) << 2;
            *(float4*)&s_w1[kkk * 128 + c4] =
                *(const float4*)&W1[(size_t)(k0 + kkk) * DD + C0 + c4];
            *(float4*)&s_w2[kkk * 128 + c4] =
                *(const float4*)&W2[(size_t)(k0 + kkk) * DD + C0 + c4];
        }
        __syncthreads();
#pragma unroll 8
        for (int k = 0; k < 32; ++k) {
            float4 xv = *(const float4*)&s_x[k * 68 + r0];
            float4 yv = *(const float4*)&s_y[k * 68 + r0];
            float4 wa = *(const float4*)&s_w1[k * 128 + c0];
            float4 wb = *(const float4*)&s_w1[k * 128 + c0 + 4];
            float4 wc = *(const float4*)&s_w2[k * 128 + c0];
            float4 wd = *(const float4*)&s_w2[k * 128 + c0 + 4];
            float xs[4]  = {xv.x, xv.y, xv.z, xv.w};
            float ys[4]  = {yv.x, yv.y, yv.z, yv.w};
            float w1s[8] = {wa.x, wa.y, wa.z, wa.w, wb.x, wb.y, wb.z, wb.w};
            float w2s[8] = {wc.x, wc.y, wc.z, wc.w, wd.x, wd.y, wd.z, wd.w};
#pragma unroll
            for (int i = 0; i < 4; ++i)
#pragma unroll
                for (int j = 0; j < 8; ++j)
                    acc[i][j] += xs[i] * w1s[j] + ys[i] * w2s[j];
        }
    }

    // leaky relu + store
#pragma unroll
    for (int i = 0; i < 4; ++i) {
#pragma unroll
        for (int jv = 0; jv < 2; ++jv) {
            float4 o;
            float v0 = acc[i][4 * jv + 0];
            float v1 = acc[i][4 * jv + 1];
            float v2 = acc[i][4 * jv + 2];
            float v3 = acc[i][4 * jv + 3];
            o.x = v0 >= 0.0f ? v0 : NEG_SLOPE * v0;
            o.y = v1 >= 0.0f ? v1 : NEG_SLOPE * v1;
            o.z = v2 >= 0.0f ? v2 : NEG_SLOPE * v2;
            o.w = v3 >= 0.0f ? v3 : NEG_SLOPE * v3;
            *(float4*)&dst[(size_t)(I0 + r0 + i) * DD + C0 + c0 + 4 * jv] = o;
        }
    }
}

// ---------------------------------------------------------------------------
// kernel_launch
// workspace (_Float16 units): uS_hi[ND] vS_hi[ND] P[2*ND] Q[2*ND] = 24 MB
// ---------------------------------------------------------------------------
extern "C" void kernel_launch(void* const* d_in, const int* in_sizes, int n_in,
                              void* d_out, int out_size, void* d_ws, size_t ws_size,
                              hipStream_t stream) {
    const float* head  = (const float*)d_in[0];
    const float* dep   = (const float*)d_in[1];
    const float* alpha = (const float*)d_in[2];
    const float* Wah   = (const float*)d_in[3];
    const float* Wad   = (const float*)d_in[4];
    const float* Wch   = (const float*)d_in[5];
    const float* Wcd   = (const float*)d_in[6];
    float* out = (float*)d_out;

    _Float16* ws    = (_Float16*)d_ws;
    _Float16* uS_hi = ws;
    _Float16* vS_hi = ws + (size_t)ND_;
    _Float16* Pbuf  = ws + (size_t)2 * ND_;   // [2][NN][DD]
    _Float16* Qbuf  = ws + (size_t)4 * ND_;   // [2][NN][DD]

    prep_split_kernel<<<512, 256, 0, stream>>>(head, dep, uS_hi, vS_hi);
    agg_mfma_kernel<<<512, 256, 0, stream>>>(alpha, uS_hi, vS_hi, Pbuf, Qbuf);
    stageB_kernel<<<512, 256, 0, stream>>>(Pbuf, Qbuf, head, dep, alpha,
                                           Wah, Wad, Wch, Wcd, out);
}

// Round 23
// 277.147 us; speedup vs baseline: 1.0492x; 1.0492x over previous
//
#include <hip/hip_runtime.h>

// Problem constants (N=8192 rows, D=256 features)
#define NN 8192
#define DD 256
#define ND_ (NN * DD)

#define NEG_SLOPE 0.1f

typedef _Float16 half8 __attribute__((ext_vector_type(8)));
typedef _Float16 half4 __attribute__((ext_vector_type(4)));
typedef float f32x4 __attribute__((ext_vector_type(4)));
typedef float f32x16 __attribute__((ext_vector_type(16)));

// async global->LDS, 16B per lane; lds dst = wave-uniform base + lane*16
__device__ __forceinline__ void ld_g2l16(const void* g, void* l) {
    __builtin_amdgcn_global_load_lds(
        (const __attribute__((address_space(1))) void*)g,
        (__attribute__((address_space(3))) void*)l, 16, 0, 0);
}

__device__ __forceinline__ unsigned pkhalf2(_Float16 a, _Float16 b) {
    unsigned short ua = __builtin_bit_cast(unsigned short, a);
    unsigned short ub = __builtin_bit_cast(unsigned short, b);
    return (unsigned)ua | ((unsigned)ub << 16);
}

// ---------------------------------------------------------------------------
// prep_split: f16 (hi-only) u = h+d, v = h-d in the SWIZZLED k-block layout
// agg consumes via linear global_load_lds:
//   element (c, k):  kb = k>>5, gd = (k>>3)&3, slot = gd ^ ((c>>1)&3)
//   offset = kb*8192 + c*32 + slot*8 + (k&7)      (f16 units)
// Grid 128 node-tiles x 4 feature-tiles = 512 blocks, 256 threads.
// ---------------------------------------------------------------------------
__global__ __launch_bounds__(256, 4)
void prep_split_kernel(const float* __restrict__ h, const float* __restrict__ d,
                       _Float16* __restrict__ uS_hi, _Float16* __restrict__ vS_hi) {
    __shared__ float s_h[64 * 68];
    __shared__ float s_d[64 * 68];
    const int b  = blockIdx.x;
    const int kt = b >> 2;          // node-tile 0..127 (64 nodes)
    const int ct = b & 3;           // feature-tile 0..3 (64 features)
    const int k0 = kt * 64;
    const int c0 = ct * 64;
    const int t  = threadIdx.x;

#pragma unroll
    for (int e = 0; e < 4; ++e) {
        int idx = e * 256 + t;
        int r   = idx >> 4;                  // node 0..63
        int c4  = (idx & 15) << 2;           // feature 0..60
        float4 hv = *(const float4*)&h[(size_t)(k0 + r) * DD + c0 + c4];
        float4 dv = *(const float4*)&d[(size_t)(k0 + r) * DD + c0 + c4];
        *(float4*)&s_h[r * 68 + c4] = hv;
        *(float4*)&s_d[r * 68 + c4] = dv;
    }
    __syncthreads();

#pragma unroll
    for (int e = 0; e < 2; ++e) {
        int idx = e * 256 + t;
        int c   = idx >> 3;                  // feature-in-tile 0..63
        int seg = idx & 7;                   // node chunk of 8 (k' = seg*8)
        half8 uh, vh;
#pragma unroll
        for (int m = 0; m < 8; ++m) {
            float hh = s_h[(seg * 8 + m) * 68 + c];
            float dd = s_d[(seg * 8 + m) * 68 + c];
            uh[m] = (_Float16)(hh + dd);
            vh[m] = (_Float16)(hh - dd);
        }
        int    cg   = c0 + c;
        int    kb   = kt * 2 + (seg >> 2);
        int    slot = (seg & 3) ^ ((cg >> 1) & 3);
        size_t go   = (size_t)kb * 8192 + (size_t)cg * 32 + slot * 8;
        *(half8*)&uS_hi[go] = uh;
        *(half8*)&vS_hi[go] = vh;
    }
}

// ---------------------------------------------------------------------------
// agg_mfma: f16x1 MFMA (32x32x16) split-K(2) partials:
//   P = (A + A^T) @ u      Q = (A^T - A) @ v       (hi terms only)
// stored f16 in Pbuf/Qbuf [2 halves][NN][DD].
//
// SD double-buffered, B TRIPLE-buffered; gl_lds issued at iteration TOP
// (maximal latency cover; safe: B[(it+1)%3]'s prior readers MFMA(it-2)
// drained via lgkmcnt(0)+barrier(it-1) before this wave reached iter it).
// All VMEM issued pre-barrier; post-barrier section is pure ds_read+MFMA.
//   queue at publish: [gl(it)^2, alpha(it+1)^6, gl(it+1)^2, alpha(it+2)^6]
//   -> vmcnt(14) retires exactly own gl_lds(it) (1 iter old, free);
//   build(it)'s auto-wait = vmcnt(10) retiring alpha(it) (2 iters old, free).
// Block 64r x 128c, 512 thr (8 waves: 0-3 P, 4-7 Q), BK=32, 128 iters.
// LDS 68KB -> 2 blocks/CU. Grid: 512 = 128 rb x 2 cb x 2 kh (bit-swizzled).
// ---------------------------------------------------------------------------
__global__ __launch_bounds__(512, 4)
void agg_mfma_kernel(const float* __restrict__ alpha,
                     const _Float16* __restrict__ uS_hi, const _Float16* __restrict__ vS_hi,
                     _Float16* __restrict__ Pbuf,   // [2][NN][DD]
                     _Float16* __restrict__ Qbuf) { // [2][NN][DD]
    // LDS carve (bytes):
    //  SD[2]: {sS [64r][40kp] , sD [64r][40kp]} f16   2*10240 = 20480
    //  B [3]: {Bu [128c][32k], Bv [128c][32k]} f16    3*16384 = 49152 -> 69632
    __shared__ __align__(16) unsigned char smem[69632];

    const int raw  = blockIdx.x;
    const int kh   = raw & 1;
    const int cb   = (raw >> 3) & 1;
    const int rb   = ((raw >> 1) & 3) | ((raw >> 4) << 2);
    const int I0   = rb * 64;
    const int C0   = cb * 128;
    const int t    = threadIdx.x;
    const int w    = t >> 6;
    const int lane = t & 63;

    const bool isP = (w < 4);
    const int  cw  = w & 3;                // 32-col band within the 128

    f32x16 acc0, acc1;
#pragma unroll
    for (int r = 0; r < 16; ++r) { acc0[r] = 0.f; acc1[r] = 0.f; }

    // build / mfma index precompute (512 thr = 16 rbase x 16 kp x 2 dup)
    const int rbase = t & 15;
    const int kp    = (t >> 4) & 15;       // k-pair: k = 2kp, 2kp+1
    const int dup   = t >> 8;              // 0 or 1
    const int rowa  = rbase + 32 * dup;    // rows rowa, rowa+16
    const int lrow  = lane & 31;
    const int lk    = (lane >> 5) << 3;    // 0 or 8
    const int kbase = kh * (NN / 2);
    const int c_local = cw * 32 + lrow;

    // rotating B-slot indices (wave-uniform scalars)
    int bcur = 0, bnext = 1;

    // ---- alpha set: 6 loads (4 col scalars + 2 row float2) = 8 VGPRs ----
#define LOAD_ALPHA(S, IT)                                                        \
    {                                                                            \
        const int kk0 = kbase + (IT) * 32 + 2 * kp;                              \
        size_t z0 = (size_t)kk0 * NN + I0;                                       \
        S##c00 = alpha[z0 + rowa];                                               \
        S##c01 = alpha[z0 + NN + rowa];                                          \
        S##c10 = alpha[z0 + rowa + 16];                                          \
        S##c11 = alpha[z0 + NN + rowa + 16];                                     \
        S##r0  = *(const float2*)&alpha[(size_t)(I0 + rowa) * NN + kk0];         \
        S##r1  = *(const float2*)&alpha[(size_t)(I0 + rowa + 16) * NN + kk0];    \
    }

    // One iteration at SD parity P consuming alpha set CUR.
#define ITER(CUR, P, IT)                                                         \
    {                                                                            \
        /* TOP: gl_lds B(IT+1) -> B[bnext] (WAR-safe vs MFMA(IT-2): those */     \
        /* reads drained via lgkmcnt(0)+barrier(IT-1) before we got here) */     \
        {                                                                        \
            size_t gb = (size_t)(kh * 128 + (((IT) + 1) & 127)) * 8192 +         \
                        cb * 4096 + (size_t)(w * 512 + lane * 8);                \
            unsigned char* bN = smem + 20480 + bnext * 16384;                    \
            ld_g2l16(uS_hi + gb, bN + w * 1024);                                 \
            ld_g2l16(vS_hi + gb, bN + 8192 + w * 1024);                          \
        }                                                                        \
        __builtin_amdgcn_sched_barrier(0);  /* pin: gl_lds first in VMEM order */\
        /* build S/D f16 pairs (CUR alpha 2 iters old -> auto-wait free) */      \
        unsigned su0 = pkhalf2((_Float16)(CUR##c00 + CUR##r0.x), (_Float16)(CUR##c01 + CUR##r0.y)); \
        unsigned du0 = pkhalf2((_Float16)(CUR##c00 - CUR##r0.x), (_Float16)(CUR##c01 - CUR##r0.y)); \
        unsigned su1 = pkhalf2((_Float16)(CUR##c10 + CUR##r1.x), (_Float16)(CUR##c11 + CUR##r1.y)); \
        unsigned du1 = pkhalf2((_Float16)(CUR##c10 - CUR##r1.x), (_Float16)(CUR##c11 - CUR##r1.y)); \
        /* ds_write S/D -> SD[P] (pitch 40 f16 = 20 u32/row) */                  \
        {                                                                        \
            unsigned* wS = (unsigned*)(smem + (P) * 10240);                      \
            unsigned* wD = (unsigned*)(smem + (P) * 10240 + 5120);               \
            wS[rowa * 20 + kp]        = su0;                                     \
            wS[(rowa + 16) * 20 + kp] = su1;                                     \
            wD[rowa * 20 + kp]        = du0;                                     \
            wD[(rowa + 16) * 20 + kp] = du1;                                     \
        }                                                                        \
        /* prefetch alpha(IT+2) back into CUR (values consumed above) */         \
        LOAD_ALPHA(CUR, (((IT) + 2) & 127))                                      \
        __builtin_amdgcn_sched_barrier(0);                                       \
        /* publish: vmcnt(14) retires exactly own gl_lds(IT) (1 iter old); */    \
        /* flush ds_writes; barrier publishes SD[P] + all waves' B[bcur] */      \
        asm volatile("s_waitcnt vmcnt(14)" ::: "memory");                        \
        asm volatile("s_waitcnt lgkmcnt(0)" ::: "memory");                       \
        __builtin_amdgcn_s_barrier();                                            \
        __builtin_amdgcn_sched_barrier(0);                                       \
        /* 4 MFMA (32x32x16), f16x1 on SD[P], B[bcur] */                         \
        {                                                                        \
            const unsigned char* sd = smem + (P) * 10240;                        \
            const _Float16* aSD = (const _Float16*)(sd + (isP ? 0 : 5120));      \
            const unsigned char* bb = smem + 20480 + bcur * 16384;               \
            const _Float16* bB  = (const _Float16*)(bb + (isP ? 0 : 8192));      \
            __builtin_amdgcn_s_setprio(1);                                       \
            _Pragma("unroll")                                                    \
            for (int s = 0; s < 2; ++s) {                                        \
                int gd = s * 2 + (lane >> 5);                                    \
                int sl = gd ^ ((c_local >> 1) & 3);                              \
                int bi = c_local * 32 + sl * 8;                                  \
                half8 aH0 = *(const half8*)&aSD[(lrow) * 40 + s * 16 + lk];      \
                half8 aH1 = *(const half8*)&aSD[(32 + lrow) * 40 + s * 16 + lk]; \
                half8 bH  = *(const half8*)&bB[bi];                              \
                acc0 = __builtin_amdgcn_mfma_f32_32x32x16_f16(aH0, bH, acc0, 0, 0, 0); \
                acc1 = __builtin_amdgcn_mfma_f32_32x32x16_f16(aH1, bH, acc1, 0, 0, 0); \
            }                                                                    \
            __builtin_amdgcn_s_setprio(0);                                       \
        }                                                                        \
        /* rotate B slots (wave-uniform scalar arithmetic) */                    \
        bcur = bnext;                                                            \
        bnext = (bnext == 2) ? 0 : (bnext + 1);                                  \
    }

    float Ac00, Ac01, Ac10, Ac11;
    float2 Ar0, Ar1;
    float Bc00, Bc01, Bc10, Bc11;
    float2 Br0, Br1;

    // ---- prologue: gl_lds B(0)->slot0; alpha(0)->A, alpha(1)->B ----
    {
        size_t gb = (size_t)(kh * 128) * 8192 + cb * 4096 +
                    (size_t)(w * 512 + lane * 8);
        unsigned char* bN = smem + 20480;
        ld_g2l16(uS_hi + gb, bN + w * 1024);
        ld_g2l16(vS_hi + gb, bN + 8192 + w * 1024);
    }
    LOAD_ALPHA(A, 0)
    LOAD_ALPHA(B, 1)

    for (int it2 = 0; it2 < 64; ++it2) {
        ITER(A, 0, (it2 * 2))
        ITER(B, 1, (it2 * 2 + 1))
    }
#undef ITER
#undef LOAD_ALPHA

    // ---- epilogue: write f16 partials ----
    // C/D layout (32x32): col = lane&31, row = (reg&3) + 8*(reg>>2) + 4*(lane>>5)
    _Float16* dst = (isP ? Pbuf : Qbuf) + (size_t)kh * ND_;
    const int colw = C0 + cw * 32 + (lane & 31);
#pragma unroll
    for (int reg = 0; reg < 16; ++reg) {
        int rr = (reg & 3) + ((reg >> 2) << 3) + ((lane >> 5) << 2);
        dst[(size_t)(I0 + rr) * DD + colw]      = (_Float16)acc0[reg];
        dst[(size_t)(I0 + 32 + rr) * DD + colw] = (_Float16)acc1[reg];
    }
}

// ---------------------------------------------------------------------------
// stageB: combine P/Q partials into agg, then
//   out = leaky_relu( agg @ W1 + Y @ W2 )
// Block tile 64 x 128, 256 threads, 4x8 accum/thread, K=256 in BK=32 chunks.
// Grid 512: sel = b>>8 (0 = head output, 1 = dependent output).
// ---------------------------------------------------------------------------
__global__ __launch_bounds__(256, 4)
void stageB_kernel(const _Float16* __restrict__ Pbuf, const _Float16* __restrict__ Qbuf,
                   const float* __restrict__ head, const float* __restrict__ dep,
                   const float* __restrict__ alpha,
                   const float* __restrict__ Wah, const float* __restrict__ Wad,
                   const float* __restrict__ Wch, const float* __restrict__ Wcd,
                   float* __restrict__ out) {
    __shared__ float smem2[12544];
    __shared__ float s_dg[64];
    float* s_x  = smem2;            // [32][68] transposed X tile
    float* s_y  = smem2 + 2176;     // [32][68]
    float* s_w1 = smem2 + 4352;     // [32][128]
    float* s_w2 = smem2 + 8448;     // [32][128] -> 12544

    int b   = blockIdx.x;
    int sel = b >> 8;
    int rem = b & 255;
    int rb  = rem >> 1;
    int cb  = rem & 1;
    int I0  = rb * 64;
    int C0  = cb * 128;

    const float* Y  = sel ? dep : head;
    const float* W1 = sel ? Wad : Wah;
    const float* W2 = sel ? Wcd : Wch;
    float* dst = out + sel * ND_;

    int t  = threadIdx.x;
    int rg = t & 15, cg = t >> 4;
    int r0 = rg * 4, c0 = cg * 8;

    if (t < 64) s_dg[t] = alpha[(size_t)(I0 + t) * NN + I0 + t];

    float acc[4][8];
#pragma unroll
    for (int i = 0; i < 4; ++i)
#pragma unroll
        for (int j = 0; j < 8; ++j) acc[i][j] = 0.0f;

    for (int it = 0; it < 8; ++it) {
        int k0 = it * 32;
        __syncthreads();
#pragma unroll
        for (int e = 0; e < 2; ++e) {
            int idx = e * 256 + t;
            int r   = idx >> 3;              // 0..63
            int k4  = (idx & 7) << 2;        // 0..28
            size_t go = (size_t)(I0 + r) * DD + k0 + k4;
            half4 p0 = *(const half4*)&Pbuf[go];
            half4 p1 = *(const half4*)&Pbuf[ND_ + go];
            half4 q0 = *(const half4*)&Qbuf[go];
            half4 q1 = *(const half4*)&Qbuf[ND_ + go];
            float4 hv = *(const float4*)&head[go];
            float4 dv = *(const float4*)&dep[go];
            float dgv = s_dg[r];
            float hj[4] = {hv.x, hv.y, hv.z, hv.w};
            float dj[4] = {dv.x, dv.y, dv.z, dv.w};
#pragma unroll
            for (int j = 0; j < 4; ++j) {
                float Pv = (float)p0[j] + (float)p1[j];
                float Qv = (float)q0[j] + (float)q1[j];
                float uu = hj[j] + dj[j];
                float x  = (sel ? 0.5f * (Pv - Qv) : 0.5f * (Pv + Qv)) - dgv * uu;
                s_x[(k4 + j) * 68 + r] = x;
                s_y[(k4 + j) * 68 + r] = sel ? dj[j] : hj[j];
            }
        }
#pragma unroll
        for (int e = 0; e < 4; ++e) {
            int idx = e * 256 + t;
            int kkk = idx >> 5;
            int c4  = (idx & 31) << 2;
            *(float4*)&s_w1[kkk * 128 + c4] =
                *(const float4*)&W1[(size_t)(k0 + kkk) * DD + C0 + c4];
            *(float4*)&s_w2[kkk * 128 + c4] =
                *(const float4*)&W2[(size_t)(k0 + kkk) * DD + C0 + c4];
        }
        __syncthreads();
#pragma unroll 8
        for (int k = 0; k < 32; ++k) {
            float4 xv = *(const float4*)&s_x[k * 68 + r0];
            float4 yv = *(const float4*)&s_y[k * 68 + r0];
            float4 wa = *(const float4*)&s_w1[k * 128 + c0];
            float4 wb = *(const float4*)&s_w1[k * 128 + c0 + 4];
            float4 wc = *(const float4*)&s_w2[k * 128 + c0];
            float4 wd = *(const float4*)&s_w2[k * 128 + c0 + 4];
            float xs[4]  = {xv.x, xv.y, xv.z, xv.w};
            float ys[4]  = {yv.x, yv.y, yv.z, yv.w};
            float w1s[8] = {wa.x, wa.y, wa.z, wa.w, wb.x, wb.y, wb.z, wb.w};
            float w2s[8] = {wc.x, wc.y, wc.z, wc.w, wd.x, wd.y, wd.z, wd.w};
#pragma unroll
            for (int i = 0; i < 4; ++i)
#pragma unroll
                for (int j = 0; j < 8; ++j)
                    acc[i][j] += xs[i] * w1s[j] + ys[i] * w2s[j];
        }
    }

    // leaky relu + store
#pragma unroll
    for (int i = 0; i < 4; ++i) {
#pragma unroll
        for (int jv = 0; jv < 2; ++jv) {
            float4 o;
            float v0 = acc[i][4 * jv + 0];
            float v1 = acc[i][4 * jv + 1];
            float v2 = acc[i][4 * jv + 2];
            float v3 = acc[i][4 * jv + 3];
            o.x = v0 >= 0.0f ? v0 : NEG_SLOPE * v0;
            o.y = v1 >= 0.0f ? v1 : NEG_SLOPE * v1;
            o.z = v2 >= 0.0f ? v2 : NEG_SLOPE * v2;
            o.w = v3 >= 0.0f ? v3 : NEG_SLOPE * v3;
            *(float4*)&dst[(size_t)(I0 + r0 + i) * DD + C0 + c0 + 4 * jv] = o;
        }
    }
}

// ---------------------------------------------------------------------------
// kernel_launch
// workspace (_Float16 units): uS_hi[ND] vS_hi[ND] P[2*ND] Q[2*ND] = 24 MB
// ---------------------------------------------------------------------------
extern "C" void kernel_launch(void* const* d_in, const int* in_sizes, int n_in,
                              void* d_out, int out_size, void* d_ws, size_t ws_size,
                              hipStream_t stream) {
    const float* head  = (const float*)d_in[0];
    const float* dep   = (const float*)d_in[1];
    const float* alpha = (const float*)d_in[2];
    const float* Wah   = (const float*)d_in[3];
    const float* Wad   = (const float*)d_in[4];
    const float* Wch   = (const float*)d_in[5];
    const float* Wcd   = (const float*)d_in[6];
    float* out = (float*)d_out;

    _Float16* ws    = (_Float16*)d_ws;
    _Float16* uS_hi = ws;
    _Float16* vS_hi = ws + (size_t)ND_;
    _Float16* Pbuf  = ws + (size_t)2 * ND_;   // [2][NN][DD]
    _Float16* Qbuf  = ws + (size_t)4 * ND_;   // [2][NN][DD]

    prep_split_kernel<<<512, 256, 0, stream>>>(head, dep, uS_hi, vS_hi);
    agg_mfma_kernel<<<512, 512, 0, stream>>>(alpha, uS_hi, vS_hi, Pbuf, Qbuf);
    stageB_kernel<<<512, 256, 0, stream>>>(Pbuf, Qbuf, head, dep, alpha,
                                           Wah, Wad, Wch, Wcd, out);
}